// Round 25
// baseline (2774.035 us; speedup 1.0000x reference)
//
#include <hip/hip_runtime.h>
#include <hip/hip_bf16.h>
#include <math.h>

// ---------------------------------------------------------------------------
// Equivariant 3D CNN (e3nn-style), 5 layers, 48^3 grid, batch 2.
// Round-25: A-reuse fix. Counters show the mid conv is LDS-read-bound:
// 144 ds_read_b128/tap/CU (~1728 cyc) vs ~360 cyc MFMA/SIMD = MfmaUtil 21%.
// Wave now owns 1y x 48z x FULL 64 co (NT=4): 6 ds_reads -> 24 MFMAs per
// tap (1:4 reuse, was 1:2). Live regs ~115 <= 170 cap (r19's spill came
// from rg[8] held prefetch + 2y acc; both gone here). Per-wave epilogue
// (conv0-verified path) drops the paired-co barriers. Staging, swizzles,
// layer-4 box-sum, conv0, setup byte-identical to r24.
// ---------------------------------------------------------------------------

typedef __attribute__((ext_vector_type(8))) short bf16x8;
typedef __attribute__((ext_vector_type(4))) float f32x4;
typedef __attribute__((ext_vector_type(4))) unsigned int u32x4;

struct TpPath { int off, ci, co, m1, l1, i2, mo, lo; float alpha; };
struct LinPath { int off, ci, co, m1, l, mo; float norm; };

// alpha = 1/sqrt(m1*1*R_BASIS)
__device__ __constant__ TpPath g_tp[19] = {
  {0,  0,  0, 1, 0, 0, 10, 0, 0.70710678f},
  {20, 0, 20, 1, 0, 0, 10, 0, 0.70710678f},
  {40, 0, 45, 1, 0, 1,  5, 1, 0.70710678f},
  {0,    0,  0, 10, 0, 0, 10, 0, 0.22360680f},
  {200,  0, 20, 10, 0, 0, 10, 0, 0.22360680f},
  {400,  0, 45, 10, 0, 1,  5, 1, 0.22360680f},
  {500, 10, 10, 10, 0, 0, 10, 0, 0.22360680f},
  {700, 10, 30, 10, 0, 1,  5, 1, 0.22360680f},
  {800, 20, 30,  5, 1, 0,  5, 1, 0.31622777f},
  {850, 20, 10,  5, 1, 1, 10, 0, 0.31622777f},
  {950, 20, 45,  5, 1, 1,  5, 1, 0.31622777f},
  {1000,35, 45,  5, 1, 0,  5, 1, 0.31622777f},
  {1050,35,  0,  5, 1, 1, 10, 0, 0.31622777f},
  {1150,35, 20,  5, 1, 1, 10, 0, 0.31622777f},
  {1250,35, 30,  5, 1, 1,  5, 1, 0.31622777f},
  {0,    0, 1, 10, 0, 0, 6, 0, 0.22360680f},
  {120, 10, 0, 10, 0, 0, 1, 0, 0.22360680f},
  {140, 20, 0,  5, 1, 1, 1, 0, 0.31622777f},
  {150, 35, 1,  5, 1, 1, 6, 0, 0.31622777f},
};

// norm = 1/sqrt(m1)
__device__ __constant__ LinPath g_lin[9] = {
  {0,  0,  0, 1, 0, 10, 1.0f},
  {10, 0, 20, 1, 0, 10, 1.0f},
  {0,   0,  0, 10, 0, 10, 0.31622777f},
  {100, 0, 20, 10, 0, 10, 0.31622777f},
  {200,10, 10, 10, 0, 10, 0.31622777f},
  {300,20, 30,  5, 1,  5, 0.44721360f},
  {325,35, 45,  5, 1,  5, 0.44721360f},
  {0,  0, 1, 10, 0, 6, 0.31622777f},
  {60,10, 0, 10, 0, 1, 0.31622777f},
};

__device__ inline float sus_f(float t) { return t > 0.f ? __expf(-1.f / t) : 0.f; }

__global__ void build_tp_kernel(const float* __restrict__ tw, float* __restrict__ kbuf,
                                int CIN, int COUT, int path_base) {
  TpPath p = g_tp[path_base + blockIdx.x];
  const int dl1 = 2 * p.l1 + 1, dlo = 2 * p.lo + 1;
  const int du = p.m1 * dl1, dw = p.mo * dlo;
  const int total = 125 * du * dw;
  const float C0 = 1.14136f * expf(2.0f);
  for (int e = threadIdx.x; e < total; e += blockDim.x) {
    int xyz = e / (du * dw);
    int rem = e % (du * dw);
    int ui = rem / dw, wk = rem % dw;
    int u = ui / dl1, i = ui % dl1;
    int w = wk / dlo, kk = wk % dlo;
    int kx = xyz / 25, ky = (xyz / 5) % 5, kz = xyz % 5;
    float cx = (float)(kx - 2), cy = (float)(ky - 2), cz = (float)(kz - 2);
    float d = sqrtf(cx * cx + cy * cy + cz * cz);
    float t = 1.2f * d;
    float e0 = C0 * sus_f(t) * sus_f(2.f - t);
    float e1 = C0 * sus_f(t - 1.f) * sus_f(3.f - t);
    float radial = e0 * tw[p.off + (0 * p.m1 + u) * p.mo + w] +
                   e1 * tw[p.off + (1 * p.m1 + u) * p.mo + w];
    float invd = (d > 0.f) ? 1.f / d : 0.f;
    const float s3 = 1.7320508f;
    float sh1[3] = { s3 * cy * invd, s3 * cz * invd, s3 * cx * invd };
    float shfac;
    if (p.l1 == 0 && p.i2 == 0)      shfac = 1.f;
    else if (p.l1 == 0)              shfac = sh1[kk];
    else if (p.i2 == 0)              shfac = (i == kk) ? 1.f : 0.f;
    else if (p.lo == 0)              shfac = sh1[i] * 0.57735027f;
    else {
      if (i == kk) shfac = 0.f;
      else {
        int j = 3 - i - kk;
        float sgn = (j == (i + 1) % 3) ? 1.f : -1.f;
        shfac = sgn * sh1[j] * 0.70710678f;
      }
    }
    kbuf[(size_t)(xyz * CIN + p.ci + ui) * COUT + p.co + wk] = p.alpha * radial * shfac;
  }
}

__global__ void set_center_kernel(const float* __restrict__ lw, float* __restrict__ kbuf,
                                  int CIN, int COUT, int lin_base, int nlin) {
  for (int l = 0; l < nlin; l++) {
    LinPath q = g_lin[lin_base + l];
    int dl = 2 * q.l + 1;
    int tot = q.m1 * q.mo * dl;
    for (int e = threadIdx.x; e < tot; e += blockDim.x) {
      int u = e / (q.mo * dl);
      int r = e % (q.mo * dl);
      int w = r / dl, ii = r % dl;
      kbuf[(size_t)(62 * CIN + q.ci + u * dl + ii) * COUT + q.co + w * dl + ii] =
          q.norm * lw[q.off + u * q.mo + w];
    }
  }
}

// fp32 kbuf [125][CIN][COUT] -> bf16 kwbT [125][64 co][64 ci], zero-padded
__global__ void convert_w(const float* __restrict__ kbuf, unsigned short* __restrict__ kwbT,
                          int CIN, int COUT) {
  int idx = blockIdx.x * 256 + threadIdx.x;
  if (idx >= 125 * 64 * 64) return;
  int tap = idx >> 12, co = (idx >> 6) & 63, ci = idx & 63;
  float v = (ci < CIN && co < COUT) ? kbuf[((size_t)tap * CIN + ci) * COUT + co] : 0.f;
  __hip_bfloat16 h = __float2bfloat16(v);
  kwbT[idx] = *(unsigned short*)&h;
}

// layer-0 tap-packed B: [5 dxi][2 mf][64 co][32 k] bf16.
__global__ void build_w0(const float* __restrict__ k0, unsigned short* __restrict__ wb0L) {
  int idx = blockIdx.x * 256 + threadIdx.x;
  if (idx >= 5 * 2 * 64 * 32) return;
  int k = idx & 31, co = (idx >> 5) & 63, mf = (idx >> 11) & 1, dxi = idx >> 12;
  float v = 0.f;
  if (co < 60) {
    if (mf == 0) {
      int dy = k >> 3, dz = k & 7;
      if (dz < 5) v = k0[(size_t)(((dxi * 5 + dy) * 5 + dz)) * 60 + co];
    } else {
      int kg = k >> 3, dz = k & 7;
      if (kg == 0 && dz < 5) v = k0[(size_t)(((dxi * 5 + 4) * 5 + dz)) * 60 + co];
    }
  }
  __hip_bfloat16 h = __float2bfloat16(v);
  wb0L[idx] = *(unsigned short*)&h;
}

__device__ inline float gelu_f(float x) {
  float inner = 0.79788456f * (x + 0.044715f * x * x * x);
  return 0.5f * x * (1.f + tanhf(inner));
}
__device__ inline float sigm_f(float x) { return 1.f / (1.f + __expf(-x)); }

// Swizzled element index in the [64 co][16 z] fp32 acc tile (4-way max).
__device__ inline int eidx(int c, int z) {
  return c * 16 + ((((z >> 2) ^ (c & 3)) << 2) | (z & 3));
}
// Swizzled packed-out dword index (conflict-free gate writes).
__device__ inline int oidx(int z, int p) { return z * 32 + (p ^ z); }
// Inverse for the coalesced copy.
__device__ inline int uidx(int e) {
  return (e & ~31) | ((e & 31) ^ ((e >> 5) & 15));
}

// Gate for one 16-z tile from swizzled acc tile -> swizzled packed dwords.
__device__ inline void gate_tile(const float* my, unsigned int* myO, int z) {
#pragma unroll
  for (int p = 0; p < 25; p++) {            // out channel pair (2p, 2p+1)
    float a0, a1;
    if (p < 5) {
      a0 = gelu_f(my[eidx(2 * p, z)]);
      a1 = gelu_f(my[eidx(2 * p + 1, z)]);
    } else if (p < 10) {
      a0 = tanhf(my[eidx(2 * p, z)]);
      a1 = tanhf(my[eidx(2 * p + 1, z)]);
    } else {
      int q0 = 2 * (p - 10), q1 = q0 + 1;
      a0 = my[eidx(30 + q0, z)] * sigm_f(my[eidx(20 + q0 / 3, z)]);
      a1 = my[eidx(30 + q1, z)] * sigm_f(my[eidx(20 + q1 / 3, z)]);
    }
    __hip_bfloat162 p2;
    p2.x = __float2bfloat16(a0);
    p2.y = __float2bfloat16(a1);
    myO[oidx(z, p)] = *(unsigned int*)&p2;
  }
#pragma unroll
  for (int p = 25; p < 32; p++) myO[oidx(z, p)] = 0u;   // ch pad 50..63
}

// Per-wave full-co epilogue (verified via conv0 since r18).
template <int NT>
__device__ inline void epilogue_gate(f32x4 (&acc)[3][NT], float* my,
                                     unsigned short* out_, int n, int x, int y,
                                     int l, int lm, int kg) {
  unsigned int* myO = (unsigned int*)(my + 1024);
#pragma unroll
  for (int zt = 0; zt < 3; zt++) {
#pragma unroll
    for (int nt = 0; nt < NT; nt++)
      *(f32x4*)(my + (lm + 16 * nt) * 16 + ((kg ^ (lm & 3)) << 2)) = acc[zt][nt];
    if (l < 16) gate_tile(my, myO, l);
    unsigned int* gout = (unsigned int*)out_ +
        ((size_t)(((n * 48 + x) * 48 + y) * 48 + 16 * zt)) * 32;
#pragma unroll 1
    for (int e = l; e < 512; e += 64) gout[e] = myO[uidx(e)];
  }
}

// MFMA implicit-GEMM mid conv. 768 thr = 12 waves (3/SIMD); wave = 1 y-row
// x 48z x FULL 64 co (NT=4): 6 ds_read_b128 -> 24 MFMA per tap (1:4 reuse).
// Tile 12y x 48z; LDS [16y][48z][64ci] linear (swizzle on global source),
// staged via global_load_lds; per-wave epilogue aliases LDS.
template <int CIN, int COUT>
__global__ __launch_bounds__(768, 3)
void conv_mfma(const unsigned short* __restrict__ act, const short* __restrict__ kwbT,
               const unsigned short* __restrict__ zguard, void* __restrict__ out_) {
  constexpr int NT = 4;                     // full co per wave
  constexpr int KC = (CIN + 31) / 32;       // 2 for CIN=50
  __shared__ __align__(16) unsigned int Albs[16 * 48 * 32];  // 98304 B

  const int tid = threadIdx.x;
  const int l = tid & 63;
  const int w = tid >> 6;        // wave 0..11: owns block-local y row w
  const int lm = l & 15;
  const int kg = l >> 4;

  const int bid = blockIdx.x;
  const int yb = bid % 4;
  const int x = (bid / 4) % 48;
  const int n = bid / (4 * 48);

  int g_off[8]; bool g_ok[8];
#pragma unroll
  for (int i = 0; i < 8; i++) {
    int e = tid + i * 768;
    int yi = e / 384;
    int rem = e % 384;
    int zin = rem >> 3, u = rem & 7;
    int usrc = u ^ (zin & 7);
    int yin = 12 * yb + yi - 2;
    g_ok[i] = (yin >= 0) && (yin < 48);
    int yc = min(max(yin, 0), 47);
    g_off[i] = (yc * 48 + zin) * 64 + usrc * 8;
  }

  f32x4 acc[3][NT];
#pragma unroll
  for (int zt = 0; zt < 3; zt++)
#pragma unroll
    for (int nt = 0; nt < NT; nt++) acc[zt][nt] = (f32x4){0.f, 0.f, 0.f, 0.f};

  const int xlo = max(x - 2, 0), xhi = min(x + 2, 47);

#pragma unroll 1
  for (int xin = xlo; xin <= xhi; ++xin) {
    __syncthreads();                            // prior compute done with Albs
    const unsigned short* pb = act + (size_t)((n * 48 + xin) * 2304) * 64;
#pragma unroll
    for (int i = 0; i < 8; i++) {               // async global -> LDS, 16B
      const unsigned short* src = g_ok[i] ? (pb + g_off[i]) : zguard;
      __builtin_amdgcn_global_load_lds(
          (const __attribute__((address_space(1))) unsigned int*)src,
          (__attribute__((address_space(3))) unsigned int*)(Albs + (size_t)(i * 768 + w * 64) * 4),
          16, 0, 0);
    }
    __syncthreads();                            // vmcnt drained -> staged

    const int dxi = xin - x + 2;
    const short* Albs_s = (const short*)Albs;
#pragma unroll 1
    for (int dy = 0; dy < 5; dy++) {
      const int yrow = w + dy;                  // 0..15
      const int tapbase = (dxi * 5 + dy) * 5;
#pragma unroll
      for (int dz = 0; dz < 5; dz++) {
        // ---- A fragments (LDS), z-edge lanes zeroed in registers ----
        bf16x8 afr[3][KC];
#pragma unroll
        for (int zt = 0; zt < 3; zt++) {
          const int zraw = 16 * zt + lm + dz - 2;
          const int zc = min(max(zraw, 0), 47);
          const bool zval = (zraw >= 0) && (zraw < 48);
          const int rowoff = (yrow * 48 + zc) * 64;
#pragma unroll
          for (int kc = 0; kc < KC; kc++) {
            int u = (4 * kc + kg) ^ (zc & 7);
            bf16x8 v = *(const bf16x8*)(Albs_s + rowoff + u * 8);
            afr[zt][kc] = zval ? v : (bf16x8)(short)0;
          }
        }
        // ---- per-nt: load B (2 frags live) then 6 MFMAs ----
        const short* wb_ = kwbT + ((size_t)(tapbase + dz) << 12) + lm * 64 + kg * 8;
#pragma unroll
        for (int nt = 0; nt < NT; nt++) {
          bf16x8 bfr[KC];
#pragma unroll
          for (int kc = 0; kc < KC; kc++)
            bfr[kc] = *(const bf16x8*)(wb_ + nt * 1024 + kc * 32);
#pragma unroll
          for (int zt = 0; zt < 3; zt++)
#pragma unroll
            for (int kc = 0; kc < KC; kc++)
              acc[zt][nt] = __builtin_amdgcn_mfma_f32_16x16x32_bf16(
                  afr[zt][kc], bfr[kc], acc[zt][nt], 0, 0, 0);
        }
      }
    }
  }

  // ---- per-wave epilogue (no cross-wave coupling): 12 x 1536 f = 73.7 KB ----
  __syncthreads();                              // all waves done reading Albs
  float* my = (float*)Albs + w * 1536;
  epilogue_gate<NT>(acc, my, (unsigned short*)out_, n, x, 12 * yb + w,
                    l, lm, kg);
}

// Layer 0 (CIN=1): taps packed into MFMA-K (round-7 structure; writes the
// 64-ch padded activation layout via the shared epilogue).
__global__ __launch_bounds__(256, 4)
void conv0_mfma(const float* __restrict__ in_, const short* __restrict__ wb0L,
                unsigned short* __restrict__ out_) {
  __shared__ float A0[8 * 72];                 // [yi][zz] fp32, zz 52..71 = 0
  __shared__ __align__(16) float outbuf0[4 * 1536];

  const int tid = threadIdx.x;
  const int l = tid & 63;
  const int w = tid >> 6;
  const int lm = l & 15;
  const int kg = l >> 4;
  const int yb = blockIdx.x % 12;
  const int x = (blockIdx.x / 12) % 48;
  const int n = blockIdx.x / (12 * 48);

  f32x4 acc[3][4];
#pragma unroll
  for (int zt = 0; zt < 3; zt++)
#pragma unroll
    for (int nt = 0; nt < 4; nt++) acc[zt][nt] = (f32x4){0.f, 0.f, 0.f, 0.f};

  for (int dxi = 0; dxi < 5; dxi++) {
    int xin = x + dxi - 2;
    if (xin < 0 || xin >= 48) continue;
    __syncthreads();
    for (int e = tid; e < 8 * 72; e += 256) {
      int yi = e / 72, zz = e % 72;
      int yin = 4 * yb + yi - 2, zin = zz - 2;
      A0[e] = (yin >= 0 && yin < 48 && zin >= 0 && zin < 48)
                  ? in_[(size_t)((n * 48 + xin) * 48 + yin) * 48 + zin] : 0.f;
    }
    __syncthreads();
#pragma unroll
    for (int mf = 0; mf < 2; mf++) {
      const short* wbp = wb0L + ((size_t)(dxi * 2 + mf) * 64 + lm) * 32 + kg * 8;
      bf16x8 bfr[4];
#pragma unroll
      for (int nt = 0; nt < 4; nt++) bfr[nt] = *(const bf16x8*)(wbp + nt * 16 * 32);
      const int row = mf ? (w + 4) : (w + kg);
#pragma unroll
      for (int zt = 0; zt < 3; zt++) {
        const float* ap = A0 + row * 72 + 16 * zt + lm;
        union { bf16x8 v; unsigned short s[8]; } af;
#pragma unroll
        for (int j = 0; j < 8; j++) {
          __hip_bfloat16 h = __float2bfloat16(ap[j]);
          af.s[j] = *(unsigned short*)&h;
        }
#pragma unroll
        for (int nt = 0; nt < 4; nt++)
          acc[zt][nt] = __builtin_amdgcn_mfma_f32_16x16x32_bf16(
              af.v, bfr[nt], acc[zt][nt], 0, 0, 0);
      }
    }
  }

  float* my = outbuf0 + w * 1536;
  epilogue_gate<4>(acc, my, out_, n, x, 4 * yb + w, l, lm, kg);
}

// ---- layer-4 box-sum path (linearity): ranges [max(0,d-2), min(47,45+d)] ----
// S1: per (n,x,y) wave, lane=ci: 5 z-range sums of bf16 act -> zs[gw][rz][64]
__global__ void sum_z(const unsigned short* __restrict__ act, float* __restrict__ zs) {
  int gw = blockIdx.x * 4 + (threadIdx.x >> 6);   // (n*48+x)*48+y, 4608 total
  int ci = threadIdx.x & 63;
  const unsigned short* p = act + (size_t)gw * 48 * 64 + ci;
  float tot = 0.f, s0 = 0.f, s1 = 0.f, s46 = 0.f, s47 = 0.f;
#pragma unroll 4
  for (int z = 0; z < 48; z++) {
    unsigned short h = p[z * 64];
    float v = __bfloat162float(*(__hip_bfloat16*)&h);
    tot += v;
    if (z == 0) s0 = v;
    if (z == 1) s1 = v;
    if (z == 46) s46 = v;
    if (z == 47) s47 = v;
  }
  float* o = zs + (size_t)gw * 320 + ci;
  o[0]   = tot - s46 - s47;   // d=0: [0,45]
  o[64]  = tot - s47;         // d=1: [0,46]
  o[128] = tot;               // d=2: [0,47]
  o[192] = tot - s0;          // d=3: [1,47]
  o[256] = tot - s0 - s1;     // d=4: [2,47]
}

// S2 (parallel): one thread per (n,x,ry,rz,ci) = 153,600; direct y-range sum.
__global__ void sum_y(const float* __restrict__ zs, float* __restrict__ ys) {
  int idx = blockIdx.x * 256 + threadIdx.x;
  if (idx >= 153600) return;
  int ci = idx & 63;
  int r = idx >> 6;                 // 2400 = 96 nx * 5 ry * 5 rz
  int rz = r % 5;
  int r2 = r / 5;
  int ry = r2 % 5;
  int nx = r2 / 5;                  // n*48+x
  int y0 = max(0, ry - 2), y1 = min(47, 45 + ry);
  float s = 0.f;
  const float* p = zs + (size_t)(nx * 48) * 320 + rz * 64 + ci;
  for (int y = y0; y <= y1; y++) s += p[(size_t)y * 320];
  ys[((size_t)nx * 25 + ry * 5 + rz) * 64 + ci] = s;
}

// S3 (parallel): one thread per (n,rx,ry,rz,ci) = 16,000; direct x-range sum.
__global__ void sum_x(const float* __restrict__ ys, float* __restrict__ xs) {
  int idx = blockIdx.x * 256 + threadIdx.x;
  if (idx >= 16000) return;
  int ci = idx & 63;
  int r = idx >> 6;                 // 250 = 2 n * 125 tap
  int tap = r % 125;
  int n = r / 125;
  int rx = tap / 25, ry = (tap / 5) % 5, rz = tap % 5;
  int x0 = max(0, rx - 2), x1 = min(47, 45 + rx);
  float s = 0.f;
  const float* p = ys + (size_t)(n * 48) * 1600 + (ry * 5 + rz) * 64 + ci;
  for (int xx = x0; xx <= x1; xx++) s += p[(size_t)xx * 1600];
  xs[(size_t)n * 8000 + tap * 64 + ci] = s;
}

// S4: out[n,co] += sum_{tap,ci} k4[tap][ci][co] * xs[n][tap][ci]  (fp32)
__global__ void contract4(const float* __restrict__ k4, const float* __restrict__ xs,
                          float* __restrict__ out) {
  int t = threadIdx.x;                            // 256 threads
  int pair = t & 15, chunk = t >> 4;              // 16 chunks of 8 taps
  if (pair >= 14) return;
  int n = pair / 7, co = pair % 7;
  int t0 = chunk * 8, t1 = min(t0 + 8, 125);
  float s = 0.f;
  for (int tap = t0; tap < t1; tap++)
    for (int ci = 0; ci < 50; ci++)
      s += k4[((size_t)tap * 50 + ci) * 7 + co] * xs[(size_t)n * 8000 + tap * 64 + ci];
  atomicAdd(&out[n * 7 + co], s);
}

extern "C" void kernel_launch(void* const* d_in, const int* in_sizes, int n_in,
                              void* d_out, int out_size, void* d_ws, size_t ws_size,
                              hipStream_t stream) {
  // setup_inputs() dict order (INTERLEAVED): x, tp_w0, lin_w0, tp_w1, lin_w1, ...
  const float* x   = (const float*)d_in[0];
  const float* tw0 = (const float*)d_in[1];
  const float* lw0 = (const float*)d_in[2];
  const float* tw1 = (const float*)d_in[3];
  const float* lw1 = (const float*)d_in[4];
  const float* tw2 = (const float*)d_in[5];
  const float* lw2 = (const float*)d_in[6];
  const float* tw3 = (const float*)d_in[7];
  const float* lw3 = (const float*)d_in[8];
  const float* tw4 = (const float*)d_in[9];
  const float* lw4 = (const float*)d_in[10];

  float* ws = (float*)d_ws;
  float* k0 = ws;                 // 125*1*60   = 7500
  float* k1 = k0 + 7500;          // 125*50*60  = 375000  (dead after convert_w -> ys)
  float* k2 = k1 + 375000;        // (dead after convert_w -> xs)
  float* k3 = k2 + 375000;
  float* k4 = k3 + 375000;        // 125*50*7 = 43750, kept fp32 for contract4
  // 64-ch-padded bf16 activations: 2*48^3*64 = 14,155,776 ushorts each
  unsigned short* actA = (unsigned short*)(ws + 1200000);
  unsigned short* actB = actA + 14155776;
  // bf16 transposed weights [125][64][64] per layer
  unsigned short* wb1 = (unsigned short*)(ws + 15360000);
  unsigned short* wb2 = wb1 + 512000;
  unsigned short* wb3 = wb2 + 512000;
  unsigned short* wb0L = wb3 + 512000;        // [5][2][64][32] = 20480
  unsigned short* zg   = wb0L + 20480;        // 16B zero guard (64B reserved)
  // layer-4 box sums (reuse dead regions): zs in actA
  float* zs = (float*)actA;
  float* ys = k1;                 // 153,600 floats <= 375,000
  float* xs = k2;                 // 16,000 floats

  hipMemsetAsync(ws, 0, (size_t)1176250 * sizeof(float), stream);
  hipMemsetAsync(zg, 0, 64, stream);
  hipMemsetAsync(d_out, 0, (size_t)out_size * sizeof(float), stream);

  build_tp_kernel<<<3, 128, 0, stream>>>(tw0, k0, 1, 60, 0);
  build_tp_kernel<<<12, 128, 0, stream>>>(tw1, k1, 50, 60, 3);
  build_tp_kernel<<<12, 128, 0, stream>>>(tw2, k2, 50, 60, 3);
  build_tp_kernel<<<12, 128, 0, stream>>>(tw3, k3, 50, 60, 3);
  build_tp_kernel<<<4, 128, 0, stream>>>(tw4, k4, 50, 7, 15);
  set_center_kernel<<<1, 256, 0, stream>>>(lw0, k0, 1, 60, 0, 2);
  set_center_kernel<<<1, 256, 0, stream>>>(lw1, k1, 50, 60, 2, 5);
  set_center_kernel<<<1, 256, 0, stream>>>(lw2, k2, 50, 60, 2, 5);
  set_center_kernel<<<1, 256, 0, stream>>>(lw3, k3, 50, 60, 2, 5);
  set_center_kernel<<<1, 256, 0, stream>>>(lw4, k4, 50, 7, 7, 2);

  convert_w<<<2000, 256, 0, stream>>>(k1, wb1, 50, 60);
  convert_w<<<2000, 256, 0, stream>>>(k2, wb2, 50, 60);
  convert_w<<<2000, 256, 0, stream>>>(k3, wb3, 50, 60);
  build_w0<<<80, 256, 0, stream>>>(k0, wb0L);

  const int grid0 = 2 * 48 * 12;  // conv0: (n, x, y-quad), 1 y per wave
  const int grid  = 2 * 48 * 4;   // mids: (n, x, 12-y block), 768 thr
  conv0_mfma<<<grid0, 256, 0, stream>>>(x, (const short*)wb0L, actA);
  conv_mfma<50, 60><<<grid, 768, 0, stream>>>(actA, (const short*)wb1, zg, actB);
  conv_mfma<50, 60><<<grid, 768, 0, stream>>>(actB, (const short*)wb2, zg, actA);
  conv_mfma<50, 60><<<grid, 768, 0, stream>>>(actA, (const short*)wb3, zg, actB);
  // layer 4 via separable box sums + fp32 contraction (actA region is dead)
  sum_z<<<1152, 256, 0, stream>>>(actB, zs);
  sum_y<<<600, 256, 0, stream>>>(zs, ys);
  sum_x<<<63, 256, 0, stream>>>(ys, xs);
  contract4<<<1, 256, 0, stream>>>(k4, xs, (float*)d_out);
}

// Round 26
// 1859.634 us; speedup vs baseline: 1.4917x; 1.4917x over previous
//
#include <hip/hip_runtime.h>
#include <hip/hip_bf16.h>
#include <math.h>

// ---------------------------------------------------------------------------
// Equivariant 3D CNN (e3nn-style), 5 layers, 48^3 grid, batch 2.
// Round-26: FINAL — locked at the round-22 configuration (verified 4x at
// ~1.86 ms total; 13x over the first working baseline).
//  - Mid convs: MFMA implicit-GEMM, 768 thr = 12 waves (3 waves/SIMD),
//    wave = y-pair x co-half (24 MFMA/tap/wave), global_load_lds staging
//    with source-side XOR swizzle, swizzled paired-co epilogue.
//    r13/r16/r19/r23/r25 perturbations in every direction all regressed:
//    this is the local optimum; the remaining ~3x to the MFMA pipe is the
//    structural barrier-drain documented in the guide (needs inline-asm
//    software pipelining, out of scope here).
//  - Layer 0: tap-packed-K MFMA kernel (CIN=1).
//  - Layer 4 by linearity: separable box-sums + fp32 contraction (~60us,
//    replaced a 428us conv; also improved absmax).
// ---------------------------------------------------------------------------

typedef __attribute__((ext_vector_type(8))) short bf16x8;
typedef __attribute__((ext_vector_type(4))) float f32x4;
typedef __attribute__((ext_vector_type(4))) unsigned int u32x4;

struct TpPath { int off, ci, co, m1, l1, i2, mo, lo; float alpha; };
struct LinPath { int off, ci, co, m1, l, mo; float norm; };

// alpha = 1/sqrt(m1*1*R_BASIS)
__device__ __constant__ TpPath g_tp[19] = {
  {0,  0,  0, 1, 0, 0, 10, 0, 0.70710678f},
  {20, 0, 20, 1, 0, 0, 10, 0, 0.70710678f},
  {40, 0, 45, 1, 0, 1,  5, 1, 0.70710678f},
  {0,    0,  0, 10, 0, 0, 10, 0, 0.22360680f},
  {200,  0, 20, 10, 0, 0, 10, 0, 0.22360680f},
  {400,  0, 45, 10, 0, 1,  5, 1, 0.22360680f},
  {500, 10, 10, 10, 0, 0, 10, 0, 0.22360680f},
  {700, 10, 30, 10, 0, 1,  5, 1, 0.22360680f},
  {800, 20, 30,  5, 1, 0,  5, 1, 0.31622777f},
  {850, 20, 10,  5, 1, 1, 10, 0, 0.31622777f},
  {950, 20, 45,  5, 1, 1,  5, 1, 0.31622777f},
  {1000,35, 45,  5, 1, 0,  5, 1, 0.31622777f},
  {1050,35,  0,  5, 1, 1, 10, 0, 0.31622777f},
  {1150,35, 20,  5, 1, 1, 10, 0, 0.31622777f},
  {1250,35, 30,  5, 1, 1,  5, 1, 0.31622777f},
  {0,    0, 1, 10, 0, 0, 6, 0, 0.22360680f},
  {120, 10, 0, 10, 0, 0, 1, 0, 0.22360680f},
  {140, 20, 0,  5, 1, 1, 1, 0, 0.31622777f},
  {150, 35, 1,  5, 1, 1, 6, 0, 0.31622777f},
};

// norm = 1/sqrt(m1)
__device__ __constant__ LinPath g_lin[9] = {
  {0,  0,  0, 1, 0, 10, 1.0f},
  {10, 0, 20, 1, 0, 10, 1.0f},
  {0,   0,  0, 10, 0, 10, 0.31622777f},
  {100, 0, 20, 10, 0, 10, 0.31622777f},
  {200,10, 10, 10, 0, 10, 0.31622777f},
  {300,20, 30,  5, 1,  5, 0.44721360f},
  {325,35, 45,  5, 1,  5, 0.44721360f},
  {0,  0, 1, 10, 0, 6, 0.31622777f},
  {60,10, 0, 10, 0, 1, 0.31622777f},
};

__device__ inline float sus_f(float t) { return t > 0.f ? __expf(-1.f / t) : 0.f; }

__global__ void build_tp_kernel(const float* __restrict__ tw, float* __restrict__ kbuf,
                                int CIN, int COUT, int path_base) {
  TpPath p = g_tp[path_base + blockIdx.x];
  const int dl1 = 2 * p.l1 + 1, dlo = 2 * p.lo + 1;
  const int du = p.m1 * dl1, dw = p.mo * dlo;
  const int total = 125 * du * dw;
  const float C0 = 1.14136f * expf(2.0f);
  for (int e = threadIdx.x; e < total; e += blockDim.x) {
    int xyz = e / (du * dw);
    int rem = e % (du * dw);
    int ui = rem / dw, wk = rem % dw;
    int u = ui / dl1, i = ui % dl1;
    int w = wk / dlo, kk = wk % dlo;
    int kx = xyz / 25, ky = (xyz / 5) % 5, kz = xyz % 5;
    float cx = (float)(kx - 2), cy = (float)(ky - 2), cz = (float)(kz - 2);
    float d = sqrtf(cx * cx + cy * cy + cz * cz);
    float t = 1.2f * d;
    float e0 = C0 * sus_f(t) * sus_f(2.f - t);
    float e1 = C0 * sus_f(t - 1.f) * sus_f(3.f - t);
    float radial = e0 * tw[p.off + (0 * p.m1 + u) * p.mo + w] +
                   e1 * tw[p.off + (1 * p.m1 + u) * p.mo + w];
    float invd = (d > 0.f) ? 1.f / d : 0.f;
    const float s3 = 1.7320508f;
    float sh1[3] = { s3 * cy * invd, s3 * cz * invd, s3 * cx * invd };
    float shfac;
    if (p.l1 == 0 && p.i2 == 0)      shfac = 1.f;
    else if (p.l1 == 0)              shfac = sh1[kk];
    else if (p.i2 == 0)              shfac = (i == kk) ? 1.f : 0.f;
    else if (p.lo == 0)              shfac = sh1[i] * 0.57735027f;
    else {
      if (i == kk) shfac = 0.f;
      else {
        int j = 3 - i - kk;
        float sgn = (j == (i + 1) % 3) ? 1.f : -1.f;
        shfac = sgn * sh1[j] * 0.70710678f;
      }
    }
    kbuf[(size_t)(xyz * CIN + p.ci + ui) * COUT + p.co + wk] = p.alpha * radial * shfac;
  }
}

__global__ void set_center_kernel(const float* __restrict__ lw, float* __restrict__ kbuf,
                                  int CIN, int COUT, int lin_base, int nlin) {
  for (int l = 0; l < nlin; l++) {
    LinPath q = g_lin[lin_base + l];
    int dl = 2 * q.l + 1;
    int tot = q.m1 * q.mo * dl;
    for (int e = threadIdx.x; e < tot; e += blockDim.x) {
      int u = e / (q.mo * dl);
      int r = e % (q.mo * dl);
      int w = r / dl, ii = r % dl;
      kbuf[(size_t)(62 * CIN + q.ci + u * dl + ii) * COUT + q.co + w * dl + ii] =
          q.norm * lw[q.off + u * q.mo + w];
    }
  }
}

// fp32 kbuf [125][CIN][COUT] -> bf16 kwbT [125][64 co][64 ci], zero-padded
__global__ void convert_w(const float* __restrict__ kbuf, unsigned short* __restrict__ kwbT,
                          int CIN, int COUT) {
  int idx = blockIdx.x * 256 + threadIdx.x;
  if (idx >= 125 * 64 * 64) return;
  int tap = idx >> 12, co = (idx >> 6) & 63, ci = idx & 63;
  float v = (ci < CIN && co < COUT) ? kbuf[((size_t)tap * CIN + ci) * COUT + co] : 0.f;
  __hip_bfloat16 h = __float2bfloat16(v);
  kwbT[idx] = *(unsigned short*)&h;
}

// layer-0 tap-packed B: [5 dxi][2 mf][64 co][32 k] bf16.
__global__ void build_w0(const float* __restrict__ k0, unsigned short* __restrict__ wb0L) {
  int idx = blockIdx.x * 256 + threadIdx.x;
  if (idx >= 5 * 2 * 64 * 32) return;
  int k = idx & 31, co = (idx >> 5) & 63, mf = (idx >> 11) & 1, dxi = idx >> 12;
  float v = 0.f;
  if (co < 60) {
    if (mf == 0) {
      int dy = k >> 3, dz = k & 7;
      if (dz < 5) v = k0[(size_t)(((dxi * 5 + dy) * 5 + dz)) * 60 + co];
    } else {
      int kg = k >> 3, dz = k & 7;
      if (kg == 0 && dz < 5) v = k0[(size_t)(((dxi * 5 + 4) * 5 + dz)) * 60 + co];
    }
  }
  __hip_bfloat16 h = __float2bfloat16(v);
  wb0L[idx] = *(unsigned short*)&h;
}

__device__ inline float gelu_f(float x) {
  float inner = 0.79788456f * (x + 0.044715f * x * x * x);
  return 0.5f * x * (1.f + tanhf(inner));
}
__device__ inline float sigm_f(float x) { return 1.f / (1.f + __expf(-x)); }

// Swizzled element index in the [64 co][16 z] fp32 acc tile (4-way max).
__device__ inline int eidx(int c, int z) {
  return c * 16 + ((((z >> 2) ^ (c & 3)) << 2) | (z & 3));
}
// Swizzled packed-out dword index (conflict-free gate writes).
__device__ inline int oidx(int z, int p) { return z * 32 + (p ^ z); }
// Inverse for the coalesced copy.
__device__ inline int uidx(int e) {
  return (e & ~31) | ((e & 31) ^ ((e >> 5) & 15));
}

// Gate for one 16-z tile from swizzled acc tile -> swizzled packed dwords.
__device__ inline void gate_tile(const float* my, unsigned int* myO, int z) {
#pragma unroll
  for (int p = 0; p < 25; p++) {            // out channel pair (2p, 2p+1)
    float a0, a1;
    if (p < 5) {
      a0 = gelu_f(my[eidx(2 * p, z)]);
      a1 = gelu_f(my[eidx(2 * p + 1, z)]);
    } else if (p < 10) {
      a0 = tanhf(my[eidx(2 * p, z)]);
      a1 = tanhf(my[eidx(2 * p + 1, z)]);
    } else {
      int q0 = 2 * (p - 10), q1 = q0 + 1;
      a0 = my[eidx(30 + q0, z)] * sigm_f(my[eidx(20 + q0 / 3, z)]);
      a1 = my[eidx(30 + q1, z)] * sigm_f(my[eidx(20 + q1 / 3, z)]);
    }
    __hip_bfloat162 p2;
    p2.x = __float2bfloat16(a0);
    p2.y = __float2bfloat16(a1);
    myO[oidx(z, p)] = *(unsigned int*)&p2;
  }
#pragma unroll
  for (int p = 25; p < 32; p++) myO[oidx(z, p)] = 0u;   // ch pad 50..63
}

// Full-acc per-wave epilogue used by conv0.
template <int NT>
__device__ inline void epilogue_gate(f32x4 (&acc)[3][NT], float* my,
                                     unsigned short* out_, int n, int x, int y,
                                     int l, int lm, int kg) {
  unsigned int* myO = (unsigned int*)(my + 1024);
#pragma unroll
  for (int zt = 0; zt < 3; zt++) {
#pragma unroll
    for (int nt = 0; nt < NT; nt++)
      *(f32x4*)(my + (lm + 16 * nt) * 16 + ((kg ^ (lm & 3)) << 2)) = acc[zt][nt];
    if (l < 16) gate_tile(my, myO, l);
    unsigned int* gout = (unsigned int*)out_ +
        ((size_t)(((n * 48 + x) * 48 + y) * 48 + 16 * zt)) * 32;
#pragma unroll 1
    for (int e = l; e < 512; e += 64) gout[e] = myO[uidx(e)];
  }
}

// MFMA implicit-GEMM conv (round-22 config). 768 thr = 12 waves (3/SIMD);
// wave: y-pair wp=w%6, co-half ch=w/6. LDS linear, global_load_lds staging.
template <int CIN, int COUT, int MODE>
__global__ __launch_bounds__(768, 3)
void conv_mfma(const unsigned short* __restrict__ act, const short* __restrict__ kwbT,
               const unsigned short* __restrict__ zguard, void* __restrict__ out_) {
  constexpr int NTH = (MODE == 0) ? 2 : 1;
  constexpr int KC = (CIN + 31) / 32;
  __shared__ __align__(16) unsigned int Albs[16 * 48 * 32];

  const int tid = threadIdx.x;
  const int l = tid & 63;
  const int w = tid >> 6;
  const int wp = (MODE == 0) ? (w % 6) : w;
  const int ch = (MODE == 0) ? (w / 6) : 0;
  const int lm = l & 15;
  const int kg = l >> 4;
  const int co_off = ch * 32;

  const int bid = blockIdx.x;
  const int yb = bid % 4;
  const int x = (bid / 4) % 48;
  const int n = bid / (4 * 48);

  int g_off[8]; bool g_ok[8];
#pragma unroll
  for (int i = 0; i < 8; i++) {
    int e = tid + i * 768;
    int yi = e / 384;
    int rem = e % 384;
    int zin = rem >> 3, u = rem & 7;
    int usrc = u ^ (zin & 7);
    int yin = 12 * yb + yi - 2;
    g_ok[i] = (yin >= 0) && (yin < 48);
    int yc = min(max(yin, 0), 47);
    g_off[i] = (yc * 48 + zin) * 64 + usrc * 8;
  }

  f32x4 acc[2][3][NTH];
#pragma unroll
  for (int yy = 0; yy < 2; yy++)
#pragma unroll
    for (int zt = 0; zt < 3; zt++)
#pragma unroll
      for (int nt = 0; nt < NTH; nt++) acc[yy][zt][nt] = (f32x4){0.f, 0.f, 0.f, 0.f};

  const int xlo = max(x - 2, 0), xhi = min(x + 2, 47);

#pragma unroll 1
  for (int xin = xlo; xin <= xhi; ++xin) {
    __syncthreads();
    const unsigned short* pb = act + (size_t)((n * 48 + xin) * 2304) * 64;
#pragma unroll
    for (int i = 0; i < 8; i++) {
      const unsigned short* src = g_ok[i] ? (pb + g_off[i]) : zguard;
      __builtin_amdgcn_global_load_lds(
          (const __attribute__((address_space(1))) unsigned int*)src,
          (__attribute__((address_space(3))) unsigned int*)(Albs + (size_t)(i * 768 + w * 64) * 4),
          16, 0, 0);
    }
    __syncthreads();

    if (MODE == 0 || w < 6) {
      const int dxi = xin - x + 2;
      const short* Albs_s = (const short*)Albs;
#pragma unroll 1
      for (int dy = 0; dy < 5; dy++) {
        const int tapbase = (dxi * 5 + dy) * 5;
#pragma unroll
        for (int dz = 0; dz < 5; dz++) {
          bf16x8 bfr[NTH * KC];
          {
            const short* wb_ = kwbT + ((size_t)(tapbase + dz) << 12) +
                               (co_off + lm) * 64 + kg * 8;
#pragma unroll
            for (int nt = 0; nt < NTH; nt++)
#pragma unroll
              for (int kc = 0; kc < KC; kc++)
                bfr[nt * KC + kc] = *(const bf16x8*)(wb_ + nt * 1024 + kc * 32);
          }
          bf16x8 afr[2][3][KC];
#pragma unroll
          for (int zt = 0; zt < 3; zt++) {
            const int zraw = 16 * zt + lm + dz - 2;
            const int zc = min(max(zraw, 0), 47);
            const bool zval = (zraw >= 0) && (zraw < 48);
#pragma unroll
            for (int yy = 0; yy < 2; yy++) {
              const int yrow = 2 * wp + yy + dy;
              const int rowoff = (yrow * 48 + zc) * 64;
#pragma unroll
              for (int kc = 0; kc < KC; kc++) {
                int u = (4 * kc + kg) ^ (zc & 7);
                bf16x8 v = *(const bf16x8*)(Albs_s + rowoff + u * 8);
                afr[yy][zt][kc] = zval ? v : (bf16x8)(short)0;
              }
            }
          }
#pragma unroll
          for (int yy = 0; yy < 2; yy++)
#pragma unroll
            for (int zt = 0; zt < 3; zt++)
#pragma unroll
              for (int nt = 0; nt < NTH; nt++)
#pragma unroll
                for (int kc = 0; kc < KC; kc++)
                  acc[yy][zt][nt] = __builtin_amdgcn_mfma_f32_16x16x32_bf16(
                      afr[yy][zt][kc], bfr[nt * KC + kc], acc[yy][zt][nt], 0, 0, 0);
        }
      }
    }
  }

  if constexpr (MODE == 0) {
    __syncthreads();
    float* base = (float*)Albs;
    int par = 0;
#pragma unroll
    for (int yy = 0; yy < 2; yy++) {
#pragma unroll
      for (int zt = 0; zt < 3; zt++) {
        float* my = base + par * 9216 + wp * 1536;
        unsigned int* myO = (unsigned int*)(my + 1024);
#pragma unroll
        for (int nt = 0; nt < NTH; nt++)
          *(f32x4*)(my + (co_off + lm + 16 * nt) * 16 + ((kg ^ (lm & 3)) << 2)) =
              acc[yy][zt][nt];
        __syncthreads();
        if (ch == 0 && l < 16) gate_tile(my, myO, l);
        __syncthreads();
        unsigned int* gout = (unsigned int*)out_ +
            ((size_t)(((n * 48 + x) * 48 + (12 * yb + 2 * wp + yy)) * 48 + 16 * zt)) * 32;
#pragma unroll
        for (int q = 0; q < 4; q++) {
          int e = ch * 256 + q * 64 + l;
          gout[e] = myO[uidx(e)];
        }
        par ^= 1;
      }
    }
  } else {
    if (w < 6) {
      float s = 0.f;
#pragma unroll
      for (int yy = 0; yy < 2; yy++)
#pragma unroll
        for (int zt = 0; zt < 3; zt++)
#pragma unroll
          for (int r = 0; r < 4; r++) s += acc[yy][zt][0][r];
      s += __shfl_xor(s, 16);
      s += __shfl_xor(s, 32);
      if (l < 7) atomicAdd(&((float*)out_)[n * 7 + l], s);
    }
  }
}

// Layer 0 (CIN=1): taps packed into MFMA-K (round-7 structure; writes the
// 64-ch padded activation layout via the shared epilogue).
__global__ __launch_bounds__(256, 4)
void conv0_mfma(const float* __restrict__ in_, const short* __restrict__ wb0L,
                unsigned short* __restrict__ out_) {
  __shared__ float A0[8 * 72];                 // [yi][zz] fp32, zz 52..71 = 0
  __shared__ __align__(16) float outbuf0[4 * 1536];

  const int tid = threadIdx.x;
  const int l = tid & 63;
  const int w = tid >> 6;
  const int lm = l & 15;
  const int kg = l >> 4;
  const int yb = blockIdx.x % 12;
  const int x = (blockIdx.x / 12) % 48;
  const int n = blockIdx.x / (12 * 48);

  f32x4 acc[3][4];
#pragma unroll
  for (int zt = 0; zt < 3; zt++)
#pragma unroll
    for (int nt = 0; nt < 4; nt++) acc[zt][nt] = (f32x4){0.f, 0.f, 0.f, 0.f};

  for (int dxi = 0; dxi < 5; dxi++) {
    int xin = x + dxi - 2;
    if (xin < 0 || xin >= 48) continue;
    __syncthreads();
    for (int e = tid; e < 8 * 72; e += 256) {
      int yi = e / 72, zz = e % 72;
      int yin = 4 * yb + yi - 2, zin = zz - 2;
      A0[e] = (yin >= 0 && yin < 48 && zin >= 0 && zin < 48)
                  ? in_[(size_t)((n * 48 + xin) * 48 + yin) * 48 + zin] : 0.f;
    }
    __syncthreads();
#pragma unroll
    for (int mf = 0; mf < 2; mf++) {
      const short* wbp = wb0L + ((size_t)(dxi * 2 + mf) * 64 + lm) * 32 + kg * 8;
      bf16x8 bfr[4];
#pragma unroll
      for (int nt = 0; nt < 4; nt++) bfr[nt] = *(const bf16x8*)(wbp + nt * 16 * 32);
      const int row = mf ? (w + 4) : (w + kg);
#pragma unroll
      for (int zt = 0; zt < 3; zt++) {
        const float* ap = A0 + row * 72 + 16 * zt + lm;
        union { bf16x8 v; unsigned short s[8]; } af;
#pragma unroll
        for (int j = 0; j < 8; j++) {
          __hip_bfloat16 h = __float2bfloat16(ap[j]);
          af.s[j] = *(unsigned short*)&h;
        }
#pragma unroll
        for (int nt = 0; nt < 4; nt++)
          acc[zt][nt] = __builtin_amdgcn_mfma_f32_16x16x32_bf16(
              af.v, bfr[nt], acc[zt][nt], 0, 0, 0);
      }
    }
  }

  float* my = outbuf0 + w * 1536;
  epilogue_gate<4>(acc, my, out_, n, x, 4 * yb + w, l, lm, kg);
}

// ---- layer-4 box-sum path (linearity): ranges [max(0,d-2), min(47,45+d)] ----
// S1: per (n,x,y) wave, lane=ci: 5 z-range sums of bf16 act -> zs[gw][rz][64]
__global__ void sum_z(const unsigned short* __restrict__ act, float* __restrict__ zs) {
  int gw = blockIdx.x * 4 + (threadIdx.x >> 6);   // (n*48+x)*48+y, 4608 total
  int ci = threadIdx.x & 63;
  const unsigned short* p = act + (size_t)gw * 48 * 64 + ci;
  float tot = 0.f, s0 = 0.f, s1 = 0.f, s46 = 0.f, s47 = 0.f;
#pragma unroll 4
  for (int z = 0; z < 48; z++) {
    unsigned short h = p[z * 64];
    float v = __bfloat162float(*(__hip_bfloat16*)&h);
    tot += v;
    if (z == 0) s0 = v;
    if (z == 1) s1 = v;
    if (z == 46) s46 = v;
    if (z == 47) s47 = v;
  }
  float* o = zs + (size_t)gw * 320 + ci;
  o[0]   = tot - s46 - s47;   // d=0: [0,45]
  o[64]  = tot - s47;         // d=1: [0,46]
  o[128] = tot;               // d=2: [0,47]
  o[192] = tot - s0;          // d=3: [1,47]
  o[256] = tot - s0 - s1;     // d=4: [2,47]
}

// S2 (parallel): one thread per (n,x,ry,rz,ci) = 153,600; direct y-range sum.
__global__ void sum_y(const float* __restrict__ zs, float* __restrict__ ys) {
  int idx = blockIdx.x * 256 + threadIdx.x;
  if (idx >= 153600) return;
  int ci = idx & 63;
  int r = idx >> 6;                 // 2400 = 96 nx * 5 ry * 5 rz
  int rz = r % 5;
  int r2 = r / 5;
  int ry = r2 % 5;
  int nx = r2 / 5;                  // n*48+x
  int y0 = max(0, ry - 2), y1 = min(47, 45 + ry);
  float s = 0.f;
  const float* p = zs + (size_t)(nx * 48) * 320 + rz * 64 + ci;
  for (int y = y0; y <= y1; y++) s += p[(size_t)y * 320];
  ys[((size_t)nx * 25 + ry * 5 + rz) * 64 + ci] = s;
}

// S3 (parallel): one thread per (n,rx,ry,rz,ci) = 16,000; direct x-range sum.
__global__ void sum_x(const float* __restrict__ ys, float* __restrict__ xs) {
  int idx = blockIdx.x * 256 + threadIdx.x;
  if (idx >= 16000) return;
  int ci = idx & 63;
  int r = idx >> 6;                 // 250 = 2 n * 125 tap
  int tap = r % 125;
  int n = r / 125;
  int rx = tap / 25, ry = (tap / 5) % 5, rz = tap % 5;
  int x0 = max(0, rx - 2), x1 = min(47, 45 + rx);
  float s = 0.f;
  const float* p = ys + (size_t)(n * 48) * 1600 + (ry * 5 + rz) * 64 + ci;
  for (int xx = x0; xx <= x1; xx++) s += p[(size_t)xx * 1600];
  xs[(size_t)n * 8000 + tap * 64 + ci] = s;
}

// S4: out[n,co] += sum_{tap,ci} k4[tap][ci][co] * xs[n][tap][ci]  (fp32)
__global__ void contract4(const float* __restrict__ k4, const float* __restrict__ xs,
                          float* __restrict__ out) {
  int t = threadIdx.x;                            // 256 threads
  int pair = t & 15, chunk = t >> 4;              // 16 chunks of 8 taps
  if (pair >= 14) return;
  int n = pair / 7, co = pair % 7;
  int t0 = chunk * 8, t1 = min(t0 + 8, 125);
  float s = 0.f;
  for (int tap = t0; tap < t1; tap++)
    for (int ci = 0; ci < 50; ci++)
      s += k4[((size_t)tap * 50 + ci) * 7 + co] * xs[(size_t)n * 8000 + tap * 64 + ci];
  atomicAdd(&out[n * 7 + co], s);
}

extern "C" void kernel_launch(void* const* d_in, const int* in_sizes, int n_in,
                              void* d_out, int out_size, void* d_ws, size_t ws_size,
                              hipStream_t stream) {
  // setup_inputs() dict order (INTERLEAVED): x, tp_w0, lin_w0, tp_w1, lin_w1, ...
  const float* x   = (const float*)d_in[0];
  const float* tw0 = (const float*)d_in[1];
  const float* lw0 = (const float*)d_in[2];
  const float* tw1 = (const float*)d_in[3];
  const float* lw1 = (const float*)d_in[4];
  const float* tw2 = (const float*)d_in[5];
  const float* lw2 = (const float*)d_in[6];
  const float* tw3 = (const float*)d_in[7];
  const float* lw3 = (const float*)d_in[8];
  const float* tw4 = (const float*)d_in[9];
  const float* lw4 = (const float*)d_in[10];

  float* ws = (float*)d_ws;
  float* k0 = ws;                 // 125*1*60   = 7500
  float* k1 = k0 + 7500;          // 125*50*60  = 375000  (dead after convert_w -> ys)
  float* k2 = k1 + 375000;        // (dead after convert_w -> xs)
  float* k3 = k2 + 375000;
  float* k4 = k3 + 375000;        // 125*50*7 = 43750, kept fp32 for contract4
  // 64-ch-padded bf16 activations: 2*48^3*64 = 14,155,776 ushorts each
  unsigned short* actA = (unsigned short*)(ws + 1200000);
  unsigned short* actB = actA + 14155776;
  // bf16 transposed weights [125][64][64] per layer
  unsigned short* wb1 = (unsigned short*)(ws + 15360000);
  unsigned short* wb2 = wb1 + 512000;
  unsigned short* wb3 = wb2 + 512000;
  unsigned short* wb0L = wb3 + 512000;        // [5][2][64][32] = 20480
  unsigned short* zg   = wb0L + 20480;        // 16B zero guard (64B reserved)
  // layer-4 box sums (reuse dead regions): zs in actA
  float* zs = (float*)actA;
  float* ys = k1;                 // 153,600 floats <= 375,000
  float* xs = k2;                 // 16,000 floats

  hipMemsetAsync(ws, 0, (size_t)1176250 * sizeof(float), stream);
  hipMemsetAsync(zg, 0, 64, stream);
  hipMemsetAsync(d_out, 0, (size_t)out_size * sizeof(float), stream);

  build_tp_kernel<<<3, 128, 0, stream>>>(tw0, k0, 1, 60, 0);
  build_tp_kernel<<<12, 128, 0, stream>>>(tw1, k1, 50, 60, 3);
  build_tp_kernel<<<12, 128, 0, stream>>>(tw2, k2, 50, 60, 3);
  build_tp_kernel<<<12, 128, 0, stream>>>(tw3, k3, 50, 60, 3);
  build_tp_kernel<<<4, 128, 0, stream>>>(tw4, k4, 50, 7, 15);
  set_center_kernel<<<1, 256, 0, stream>>>(lw0, k0, 1, 60, 0, 2);
  set_center_kernel<<<1, 256, 0, stream>>>(lw1, k1, 50, 60, 2, 5);
  set_center_kernel<<<1, 256, 0, stream>>>(lw2, k2, 50, 60, 2, 5);
  set_center_kernel<<<1, 256, 0, stream>>>(lw3, k3, 50, 60, 2, 5);
  set_center_kernel<<<1, 256, 0, stream>>>(lw4, k4, 50, 7, 7, 2);

  convert_w<<<2000, 256, 0, stream>>>(k1, wb1, 50, 60);
  convert_w<<<2000, 256, 0, stream>>>(k2, wb2, 50, 60);
  convert_w<<<2000, 256, 0, stream>>>(k3, wb3, 50, 60);
  build_w0<<<80, 256, 0, stream>>>(k0, wb0L);

  const int grid0 = 2 * 48 * 12;  // conv0: (n, x, y-quad), 1 y per wave
  const int grid  = 2 * 48 * 4;   // mids: (n, x, 12-y block), 768 thr
  conv0_mfma<<<grid0, 256, 0, stream>>>(x, (const short*)wb0L, actA);
  conv_mfma<50, 60, 0><<<grid, 768, 0, stream>>>(actA, (const short*)wb1, zg, actB);
  conv_mfma<50, 60, 0><<<grid, 768, 0, stream>>>(actB, (const short*)wb2, zg, actA);
  conv_mfma<50, 60, 0><<<grid, 768, 0, stream>>>(actA, (const short*)wb3, zg, actB);
  // layer 4 via separable box sums + fp32 contraction (actA region is dead)
  sum_z<<<1152, 256, 0, stream>>>(actB, zs);
  sum_y<<<600, 256, 0, stream>>>(zs, ys);
  sum_x<<<63, 256, 0, stream>>>(ys, xs);
  contract4<<<1, 256, 0, stream>>>(k4, xs, (float*)d_out);
}